// Round 6
// baseline (759.713 us; speedup 1.0000x reference)
//
#include <hip/hip_runtime.h>

#define BN 13248
#define NE 211968

typedef __attribute__((ext_vector_type(8))) short bf16x8;
typedef __attribute__((ext_vector_type(4))) float f32x4;

__device__ __forceinline__ f32x4 mfma16(bf16x8 a, bf16x8 b, f32x4 c) {
  return __builtin_amdgcn_mfma_f32_16x16x32_bf16(a, b, c, 0, 0, 0);
}

__device__ __forceinline__ unsigned short to_bf16(float v) {
  unsigned bits = __float_as_uint(v);
  return (unsigned short)((bits + 0x7FFFu + ((bits >> 16) & 1u)) >> 16);   // RNE
}

__device__ __forceinline__ float fast_tanh(float x) {
  float e2 = __expf(2.f * x);
  return 1.f - 2.f / (e2 + 1.f);   // inf-safe
}
__device__ __forceinline__ float fast_sig(float x) {
  return 1.f / (1.f + __expf(-x));
}

// ---------------- CSR build ----------------
__global__ void k_count(const int* __restrict__ src, const int* __restrict__ dst,
                        int* __restrict__ cur_f, int* __restrict__ cur_b) {
  int e = blockIdx.x * 256 + threadIdx.x;
  if (e < NE) {
    atomicAdd(&cur_f[dst[e]], 1);
    atomicAdd(&cur_b[src[e]], 1);
  }
}

__global__ void k_scan(int* __restrict__ cur_f, int* __restrict__ row_f,
                       int* __restrict__ cur_b, int* __restrict__ row_b) {
  __shared__ int sdata[1024];
  int tid = threadIdx.x;
  for (int which = 0; which < 2; ++which) {
    int* cnt = which ? cur_b : cur_f;
    int* row = which ? row_b : row_f;
    int base = tid * 13;
    int vals[13];
    int tot = 0;
    for (int k = 0; k < 13; ++k) {
      int idx = base + k;
      int v = (idx < BN) ? cnt[idx] : 0;
      vals[k] = v; tot += v;
    }
    sdata[tid] = tot;
    __syncthreads();
    for (int off = 1; off < 1024; off <<= 1) {
      int add = (tid >= off) ? sdata[tid - off] : 0;
      __syncthreads();
      sdata[tid] += add;
      __syncthreads();
    }
    int running = sdata[tid] - tot;  // exclusive
    for (int k = 0; k < 13; ++k) {
      int idx = base + k;
      if (idx < BN) { row[idx] = running; cnt[idx] = running; running += vals[k]; }
    }
    if (tid == 1023) row[BN] = sdata[1023];
    __syncthreads();
  }
}

// packed edge records: ce[e] = {neighbor, weight_bits}
__global__ void k_fill(const int* __restrict__ src, const int* __restrict__ dst,
                       const float* __restrict__ w,
                       int* __restrict__ cur_f, int2* __restrict__ ce_f,
                       int* __restrict__ cur_b, int2* __restrict__ ce_b) {
  int e = blockIdx.x * 256 + threadIdx.x;
  if (e < NE) {
    int s = src[e], t = dst[e];
    int wb = __float_as_int(w[e]);
    int p = atomicAdd(&cur_f[t], 1); ce_f[p] = make_int2(s, wb);
    int q = atomicAdd(&cur_b[s], 1); ce_b[q] = make_int2(t, wb);
  }
}

// ---------------- init linear ----------------
__global__ void k_init(const float* __restrict__ x, const float* __restrict__ iw,
                       const float* __restrict__ ib, float* __restrict__ h) {
  int idx = blockIdx.x * 256 + threadIdx.x;
  if (idx >= BN * 13 * 32) return;
  int c = idx & 31;
  int r = idx >> 5;          // r = tau*BN + n
  int n = r % BN;
  int tau = r / BN;
  float x0 = x[(n * 13 + tau) * 2 + 0];
  float x1 = x[(n * 13 + tau) * 2 + 1];
  h[idx] = fmaf(x0, iw[c], fmaf(x1, iw[32 + c], ib[c]));
}

// ---------------- weight pre-pack (bf16 B^T for all MFMA GEMMs) ----------------
__global__ void k_pack(const float* __restrict__ skip_w, const float* __restrict__ skip_b,
                       const float* __restrict__ w0, const float* __restrict__ w1,
                       const float* __restrict__ gcn_w,
                       unsigned short* __restrict__ SWb, unsigned short* __restrict__ W0T,
                       unsigned short* __restrict__ W1T, float* __restrict__ bsum,
                       unsigned short* __restrict__ GgT) {
  int id = blockIdx.x * 256 + threadIdx.x;
  if (id < 65536) {          // SWb[j][k=l*32+c] = skip_w[l][j][c]
    int j = id >> 8, k = id & 255;
    SWb[id] = to_bf16(skip_w[((k >> 5) * 256 + j) * 32 + (k & 31)]);
  }
  if (id < 131072) {         // W0T[jo][k] = w0[k][jo]
    int jo = id >> 8, k = id & 255;
    W0T[id] = to_bf16(w0[k * 512 + jo]);
  }
  if (id < 8192) {           // W1T[n][k] = w1[k][n], n padded to 16
    int n = id >> 9, k = id & 511;
    W1T[id] = (n < 12) ? to_bf16(w1[k * 12 + n]) : (unsigned short)0;
  }
  if (id < 256) {
    float s = 0.f;
    for (int l = 0; l < 8; ++l) s += skip_b[l * 256 + id];
    bsum[id] = s;
  }
  if (id < 49152) {          // GgT[l][co][k=a*32+ci] = gcn_w[l][a][ci][co]
    int l = id / 6144, rem = id % 6144;
    int co = rem / 192, k = rem % 192;
    int a = k >> 5, ci = k & 31;
    GgT[id] = to_bf16(gcn_w[((l * 6 + a) * 32 + ci) * 32 + co]);
  }
}

// ---------------- gated TCN: writes bf16 t, node-major, zero-padded to TPAD ----------------
template<int LIN, int D, int TPAD>
__global__ __launch_bounds__(256) void k_tcn(const float* __restrict__ h_in, unsigned short* __restrict__ t_out,
    const float* __restrict__ fw, const float* __restrict__ fb,
    const float* __restrict__ gw, const float* __restrict__ gb) {
  constexpr int LOUT = LIN - D;
  __shared__ __align__(16) float wq[32 * 32 * 4];   // [(ci*32+co)*4 + {f0,f1,g0,g1}]
  __shared__ float hl[8][LIN * 32];
  int tid = threadIdx.x;
  for (int f = tid; f < 4096; f += 256) {
    int e = f & 3, co = (f >> 2) & 31, ci = f >> 7;
    const float* srcw = (e < 2) ? fw : gw;
    wq[f] = srcw[(co * 32 + ci) * 2 + (e & 1)];
  }
  int n0 = blockIdx.x * 8;
  for (int i = tid; i < 8 * LIN * 32; i += 256) {
    int c = i & 31, r = i >> 5;
    int nl = r / LIN, tau = r % LIN;
    hl[nl][tau * 32 + c] = h_in[(tau * BN + n0 + nl) * 32 + c];
  }
  __syncthreads();
  int nl = tid >> 5, co = tid & 31;
  int n = n0 + nl;
  float accf[LOUT], accg[LOUT];
  float fbv = fb[co], gbv = gb[co];
#pragma unroll
  for (int j = 0; j < LOUT; ++j) { accf[j] = fbv; accg[j] = gbv; }
#pragma unroll
  for (int ci = 0; ci < 32; ++ci) {
    float4 wv = *(const float4*)&wq[(ci * 32 + co) * 4];
    float xr[LIN];
#pragma unroll
    for (int t = 0; t < LIN; ++t) xr[t] = hl[nl][t * 32 + ci];
#pragma unroll
    for (int j = 0; j < LOUT; ++j) {
      accf[j] = fmaf(xr[j], wv.x, accf[j]);
      accf[j] = fmaf(xr[j + D], wv.y, accf[j]);
      accg[j] = fmaf(xr[j], wv.z, accg[j]);
      accg[j] = fmaf(xr[j + D], wv.w, accg[j]);
    }
  }
#pragma unroll
  for (int j = 0; j < TPAD; ++j) {
    float v = (j < LOUT) ? fast_tanh(accf[j < LOUT ? j : 0]) * fast_sig(accg[j < LOUT ? j : 0]) : 0.f;
    t_out[(n * TPAD + j) * 32 + co] = (j < LOUT) ? to_bf16(v) : (unsigned short)0;
  }
}

// ---------------- diffusion conv: one dispatch per layer, all tau ----------------
__device__ __forceinline__ void bf4_fma3(uint2 u, float w1, float w2, float w3,
                                         float4* A0, float4* A1, float4* A2) {
  float v0 = __uint_as_float(u.x << 16);
  float v1 = __uint_as_float(u.x & 0xFFFF0000u);
  float v2 = __uint_as_float(u.y << 16);
  float v3 = __uint_as_float(u.y & 0xFFFF0000u);
  A0->x = fmaf(w1, v0, A0->x); A0->y = fmaf(w1, v1, A0->y);
  A0->z = fmaf(w1, v2, A0->z); A0->w = fmaf(w1, v3, A0->w);
  A1->x = fmaf(w2, v0, A1->x); A1->y = fmaf(w2, v1, A1->y);
  A1->z = fmaf(w2, v2, A1->z); A1->w = fmaf(w2, v3, A1->w);
  A2->x = fmaf(w3, v0, A2->x); A2->y = fmaf(w3, v1, A2->y);
  A2->z = fmaf(w3, v2, A2->z); A2->w = fmaf(w3, v3, A2->w);
}

// all 32 lanes of a node-group load the same ce[e] (broadcast, L2-hot); no shuffles
template<int TPAD, int NT>
__device__ __forceinline__ void gather_dir(const unsigned short* __restrict__ t_in,
    int e0, int e1, const int2* __restrict__ ce, int rowoff0, float4 (*A)[NT]) {
  constexpr int EB = (NT >= 3) ? 2 : 4;
  int e = e0;
  for (; e + EB <= e1; e += EB) {
    int2 c[EB];
    uint2 u[EB][NT];
#pragma unroll
    for (int k = 0; k < EB; ++k) c[k] = ce[e + k];
#pragma unroll
    for (int k = 0; k < EB; ++k) {
      const unsigned short* p = t_in + c[k].x * (TPAD * 32) + rowoff0;
#pragma unroll
      for (int j = 0; j < NT; ++j) u[k][j] = *(const uint2*)(p + j * 32);
    }
#pragma unroll
    for (int k = 0; k < EB; ++k) {
      float w1 = __int_as_float(c[k].y);
      float w2 = w1 * w1, w3 = w2 * w1;
#pragma unroll
      for (int j = 0; j < NT; ++j)
        bf4_fma3(u[k][j], w1, w2, w3, &A[0][j], &A[1][j], &A[2][j]);
    }
  }
  for (; e < e1; ++e) {
    int2 c = ce[e];
    float w1 = __int_as_float(c.y);
    float w2 = w1 * w1, w3 = w2 * w1;
    const unsigned short* p = t_in + c.x * (TPAD * 32) + rowoff0;
#pragma unroll
    for (int j = 0; j < NT; ++j) {
      uint2 u = *(const uint2*)(p + j * 32);
      bf4_fma3(u, w1, w2, w3, &A[0][j], &A[1][j], &A[2][j]);
    }
  }
}

#define ZSTRIDE 200   // halves; rows offset banks by 4 -> worst case mild, b128-phased

template<int LOUT, int D, int TPAD>
__global__ __launch_bounds__(128, 4) void k_agg(const unsigned short* __restrict__ t_in,
    const float* __restrict__ h_in, float* __restrict__ h_out, float* __restrict__ lastcol,
    const int* __restrict__ row_f, const int2* __restrict__ ce_f,
    const int* __restrict__ row_b, const int2* __restrict__ ce_b,
    const unsigned short* __restrict__ WgT,   // [32][192] bf16 B^T for this layer
    const float* __restrict__ bias) {
  constexpr int NT = TPAD / 4;
  __shared__ __align__(16) unsigned short Zl[4 * TPAD * ZSTRIDE];   // <= 19.2 KB
  int tid = threadIdx.x;
  int nl = tid >> 5, lane32 = tid & 31;
  int tl = lane32 >> 3;              // tau slot 0..3; lane covers tau = tl*NT + j
  int c4 = (lane32 & 7) << 2;        // 4-channel group
  int n0 = blockIdx.x * 4;
  int n = n0 + nl;                   // BN % 4 == 0
  int rowoff0 = (tl * NT) * 32 + c4;
  int ef0 = row_f[n], ef1 = row_f[n + 1];
  int eb0 = row_b[n], eb1 = row_b[n + 1];
  float4 accf[3][NT], accb[3][NT];
#pragma unroll
  for (int a = 0; a < 3; ++a)
#pragma unroll
    for (int j = 0; j < NT; ++j) {
      accf[a][j] = make_float4(0.f, 0.f, 0.f, 0.f);
      accb[a][j] = make_float4(0.f, 0.f, 0.f, 0.f);
    }
  gather_dir<TPAD, NT>(t_in, ef0, ef1, ce_f, rowoff0, accf);
  gather_dir<TPAD, NT>(t_in, eb0, eb1, ce_b, rowoff0, accb);
  // z -> LDS bf16 A-tile: row m = nl*TPAD + tl*NT + j, k = a*32 + c4
#pragma unroll
  for (int j = 0; j < NT; ++j) {
    int m = nl * TPAD + tl * NT + j;
#pragma unroll
    for (int a = 0; a < 3; ++a) {
      ushort4 pf, pb;
      pf.x = to_bf16(accf[a][j].x); pf.y = to_bf16(accf[a][j].y);
      pf.z = to_bf16(accf[a][j].z); pf.w = to_bf16(accf[a][j].w);
      pb.x = to_bf16(accb[a][j].x); pb.y = to_bf16(accb[a][j].y);
      pb.z = to_bf16(accb[a][j].z); pb.w = to_bf16(accb[a][j].w);
      *(ushort4*)(&Zl[m * ZSTRIDE + a * 32 + c4]) = pf;
      *(ushort4*)(&Zl[m * ZSTRIDE + (a + 3) * 32 + c4]) = pb;
    }
  }
  __syncthreads();
  // MFMA: D[4*TPAD rows][32 co] = Z[4*TPAD][192] @ Wg[192][32]
  // TPAD/2 units of (mt, nt) over 2 waves; wave w takes units w*NT..w*NT+NT-1
  int wave = tid >> 6, lane = tid & 63;
  int m16 = lane & 15, q = lane >> 4;
#pragma unroll
  for (int i = 0; i < NT; ++i) {
    int u = wave * NT + i;
    int mt = u >> 1, nt = u & 1;
    f32x4 dacc = (f32x4){0.f, 0.f, 0.f, 0.f};
#pragma unroll
    for (int ks = 0; ks < 6; ++ks) {
      bf16x8 av = *(const bf16x8*)(&Zl[(mt * 16 + m16) * ZSTRIDE + ks * 32 + q * 8]);
      bf16x8 bv = *(const bf16x8*)(WgT + (nt * 16 + m16) * 192 + ks * 32 + q * 8);
      dacc = mfma16(av, bv, dacc);
    }
    int co = nt * 16 + m16;
    float bco = bias[co];
#pragma unroll
    for (int r = 0; r < 4; ++r) {
      int mm = mt * 16 + q * 4 + r;           // C/D: col=lane&15, row=q*4+r
      int node = n0 + mm / TPAD;
      int tau = mm % TPAD;
      if (tau < LOUT) {
        float rres = h_in[((tau + D) * BN + node) * 32 + co];   // residual
        float o = dacc[r] + bco + rres;
        h_out[(tau * BN + node) * 32 + co] = o;
        if (tau == LOUT - 1) lastcol[node * 32 + co] = o;
      }
    }
  }
}

// ------------- fused MFMA head -------------
__device__ __forceinline__ bf16x8 ldsA(const unsigned short* buf, int stride, int row, int ks, int q) {
  int unit = ks * 4 + q;
  int addr = row * stride + ((unit ^ (row & 7)) << 3);
  return *(const bf16x8*)(buf + addr);
}

__global__ __launch_bounds__(256) void k_final(const float* __restrict__ lastcol,
    const unsigned short* __restrict__ SWb, const unsigned short* __restrict__ W0T,
    const unsigned short* __restrict__ W1T, const float* __restrict__ bsum,
    const float* __restrict__ b0, const float* __restrict__ b1,
    float* __restrict__ out) {
  __shared__ __align__(16) unsigned short Z[32 * 256];   // GEMM1 A, then relu(skip) (GEMM2 A)
  __shared__ __align__(16) unsigned short H[32 * 512];   // GEMM3 A
  int tid = threadIdx.x;
  int wave = tid >> 6, lane = tid & 63;
  int m16 = lane & 15, q = lane >> 4;
  int n0 = blockIdx.x * 32;
#pragma unroll
  for (int it = 0; it < 32; ++it) {
    int id = it * 256 + tid;
    int m = id >> 8, k = id & 255;
    float v = lastcol[((k >> 5) * BN + n0 + m) * 32 + (k & 31)];
    Z[m * 256 + (((k >> 3) ^ (m & 7)) << 3) + (k & 7)] = to_bf16(v);
  }
  __syncthreads();
  f32x4 acc1[2][4];
#pragma unroll
  for (int mt = 0; mt < 2; ++mt)
#pragma unroll
    for (int i = 0; i < 4; ++i) acc1[mt][i] = (f32x4){0.f, 0.f, 0.f, 0.f};
#pragma unroll
  for (int ks = 0; ks < 8; ++ks) {
    bf16x8 a0 = ldsA(Z, 256, m16, ks, q);
    bf16x8 a1 = ldsA(Z, 256, 16 + m16, ks, q);
#pragma unroll
    for (int i = 0; i < 4; ++i) {
      int j = (wave * 4 + i) * 16 + m16;
      bf16x8 b = *(const bf16x8*)(SWb + j * 256 + ks * 32 + q * 8);
      acc1[0][i] = mfma16(a0, b, acc1[0][i]);
      acc1[1][i] = mfma16(a1, b, acc1[1][i]);
    }
  }
  __syncthreads();
#pragma unroll
  for (int i = 0; i < 4; ++i) {
    int j = (wave * 4 + i) * 16 + m16;
    float bs = bsum[j];
#pragma unroll
    for (int mt = 0; mt < 2; ++mt)
#pragma unroll
      for (int r = 0; r < 4; ++r) {
        int row = mt * 16 + q * 4 + r;
        float v = fmaxf(acc1[mt][i][r] + bs, 0.f);
        Z[row * 256 + (((j >> 3) ^ (row & 7)) << 3) + (j & 7)] = to_bf16(v);
      }
  }
  __syncthreads();
  f32x4 acc2[2][8];
#pragma unroll
  for (int mt = 0; mt < 2; ++mt)
#pragma unroll
    for (int i = 0; i < 8; ++i) acc2[mt][i] = (f32x4){0.f, 0.f, 0.f, 0.f};
#pragma unroll
  for (int ks = 0; ks < 8; ++ks) {
    bf16x8 a0 = ldsA(Z, 256, m16, ks, q);
    bf16x8 a1 = ldsA(Z, 256, 16 + m16, ks, q);
#pragma unroll
    for (int i = 0; i < 8; ++i) {
      int jo = (wave * 8 + i) * 16 + m16;
      bf16x8 b = *(const bf16x8*)(W0T + jo * 256 + ks * 32 + q * 8);
      acc2[0][i] = mfma16(a0, b, acc2[0][i]);
      acc2[1][i] = mfma16(a1, b, acc2[1][i]);
    }
  }
#pragma unroll
  for (int i = 0; i < 8; ++i) {
    int jo = (wave * 8 + i) * 16 + m16;
    float b0v = b0[jo];
#pragma unroll
    for (int mt = 0; mt < 2; ++mt)
#pragma unroll
      for (int r = 0; r < 4; ++r) {
        int row = mt * 16 + q * 4 + r;
        float v = fmaxf(acc2[mt][i][r] + b0v, 0.f);
        H[row * 512 + (((jo >> 3) ^ (row & 7)) << 3) + (jo & 7)] = to_bf16(v);
      }
  }
  __syncthreads();
  if (wave < 2) {
    f32x4 acc3 = (f32x4){0.f, 0.f, 0.f, 0.f};
#pragma unroll
    for (int ks = 0; ks < 16; ++ks) {
      bf16x8 a = ldsA(H, 512, wave * 16 + m16, ks, q);
      bf16x8 b = *(const bf16x8*)(W1T + m16 * 512 + ks * 32 + q * 8);
      acc3 = mfma16(a, b, acc3);
    }
    if (m16 < 12) {
      float bv = b1[m16];
#pragma unroll
      for (int r = 0; r < 4; ++r)
        out[(n0 + wave * 16 + q * 4 + r) * 12 + m16] = acc3[r] + bv;
    }
  }
}

extern "C" void kernel_launch(void* const* d_in, const int* in_sizes, int n_in,
                              void* d_out, int out_size, void* d_ws, size_t ws_size,
                              hipStream_t stream) {
  const float* x      = (const float*)d_in[0];
  const int*   esrc   = (const int*)d_in[1];
  const int*   edst   = (const int*)d_in[2];
  const float* ew     = (const float*)d_in[3];
  const float* init_w = (const float*)d_in[4];
  const float* init_b = (const float*)d_in[5];
  const float* filt_w = (const float*)d_in[6];
  const float* filt_b = (const float*)d_in[7];
  const float* gate_w = (const float*)d_in[8];
  const float* gate_b = (const float*)d_in[9];
  const float* gcn_w  = (const float*)d_in[10];
  const float* gcn_b  = (const float*)d_in[11];
  const float* skip_w = (const float*)d_in[12];
  const float* skip_b = (const float*)d_in[13];
  const float* w0     = (const float*)d_in[14];
  const float* b0     = (const float*)d_in[15];
  const float* w1     = (const float*)d_in[16];
  const float* b1     = (const float*)d_in[17];
  float* out = (float*)d_out;

  float* base = (float*)d_ws;
  float* hA      = base;                       // 13*BN*32 f32
  float* hB      = hA + 13 * BN * 32;          // 13*BN*32 f32
  float* tbuf    = hB + 13 * BN * 32;          // region reused: bf16 t (<=12*BN*32 halves) + packed weights
  float* lastcol = tbuf + 12 * BN * 32;        // 8*BN*32 f32
  int* row_f = (int*)(lastcol + 8 * BN * 32);  // BN+1
  int* row_b = row_f + (BN + 1);               // BN+1
  int* cur_f = row_b + (BN + 1);               // BN
  int* cur_b = cur_f + BN;                     // BN
  int2* ce_f = (int2*)(cur_b + BN);            // NE int2
  int2* ce_b = ce_f + NE;                      // NE int2
  unsigned short* tbuf_u = (unsigned short*)tbuf;
  unsigned short* SWb = tbuf_u + 16 * BN * 32;   // 65536 halves
  unsigned short* W0T = SWb + 65536;             // 131072 halves
  unsigned short* W1T = W0T + 131072;            // 8192 halves
  float* bsumv = (float*)(W1T + 8192);           // 256 f32
  unsigned short* GgT = (unsigned short*)(bsumv + 256);  // 49152 halves

  hipMemsetAsync(cur_f, 0, 2 * BN * sizeof(int), stream);
  const int egrid = (NE + 255) / 256;
  k_count<<<egrid, 256, 0, stream>>>(esrc, edst, cur_f, cur_b);
  k_scan<<<1, 1024, 0, stream>>>(cur_f, row_f, cur_b, row_b);
  k_fill<<<egrid, 256, 0, stream>>>(esrc, edst, ew, cur_f, ce_f, cur_b, ce_b);
  k_init<<<(BN * 13 * 32 + 255) / 256, 256, 0, stream>>>(x, init_w, init_b, hA);
  k_pack<<<512, 256, 0, stream>>>(skip_w, skip_b, w0, w1, gcn_w, SWb, W0T, W1T, bsumv, GgT);

#define LAYER(l, LIN, DD, TP, hin, hout) \
  k_tcn<LIN, DD, TP><<<BN / 8, 256, 0, stream>>>(hin, tbuf_u, filt_w + l * 2048, filt_b + l * 32, \
                                                 gate_w + l * 2048, gate_b + l * 32); \
  k_agg<LIN - DD, DD, TP><<<BN / 4, 128, 0, stream>>>(tbuf_u, hin, hout, \
      lastcol + l * BN * 32, row_f, ce_f, row_b, ce_b, GgT + l * 6144, gcn_b + l * 32);

  LAYER(0, 13, 1, 12, hA, hB)
  LAYER(1, 12, 2, 12, hB, hA)
  LAYER(2, 10, 1, 12, hA, hB)
  LAYER(3,  9, 2,  8, hB, hA)
  LAYER(4,  7, 1,  8, hA, hB)
  LAYER(5,  6, 2,  4, hB, hA)
  LAYER(6,  4, 1,  4, hA, hB)
  LAYER(7,  3, 2,  4, hB, hA)
#undef LAYER

  k_final<<<BN / 32, 256, 0, stream>>>(lastcol, SWb, W0T, W1T, bsumv, b0, b1, out);
}

// Round 7
// 740.313 us; speedup vs baseline: 1.0262x; 1.0262x over previous
//
#include <hip/hip_runtime.h>
#include <hip/hip_fp16.h>

#define BN 13248
#define NE 211968
#define ZSTRIDE 200   // halves per Z row (192 + 8 pad)

typedef __attribute__((ext_vector_type(8))) short bf16x8;
typedef __attribute__((ext_vector_type(8))) _Float16 f16x8;
typedef __attribute__((ext_vector_type(4))) float f32x4;

__device__ __forceinline__ f32x4 mfma16b(bf16x8 a, bf16x8 b, f32x4 c) {
  return __builtin_amdgcn_mfma_f32_16x16x32_bf16(a, b, c, 0, 0, 0);
}
__device__ __forceinline__ f32x4 mfma16h(f16x8 a, f16x8 b, f32x4 c) {
  return __builtin_amdgcn_mfma_f32_16x16x32_f16(a, b, c, 0, 0, 0);
}

__device__ __forceinline__ unsigned short to_bf16(float v) {
  unsigned bits = __float_as_uint(v);
  return (unsigned short)((bits + 0x7FFFu + ((bits >> 16) & 1u)) >> 16);
}
__device__ __forceinline__ unsigned short to_f16(float v) {
  union { __half h; unsigned short s; } u; u.h = __float2half(v); return u.s;
}
__device__ __forceinline__ unsigned h2u(__half2 h) {
  union { __half2 h; unsigned u; } v; v.h = h; return v.u;
}
__device__ __forceinline__ __half2 u2h(unsigned u) {
  union { unsigned u; __half2 h; } v; v.u = u; return v.h;
}

__device__ __forceinline__ float fast_tanh(float x) {
  float e2 = __expf(2.f * x);
  return 1.f - 2.f / (e2 + 1.f);
}
__device__ __forceinline__ float fast_sig(float x) {
  return 1.f / (1.f + __expf(-x));
}

// ---------------- CSR build ----------------
__global__ void k_count(const int* __restrict__ src, const int* __restrict__ dst,
                        int* __restrict__ cur_f, int* __restrict__ cur_b) {
  int e = blockIdx.x * 256 + threadIdx.x;
  if (e < NE) {
    atomicAdd(&cur_f[dst[e]], 1);
    atomicAdd(&cur_b[src[e]], 1);
  }
}

__global__ void k_scan(int* __restrict__ cur_f, int* __restrict__ row_f,
                       int* __restrict__ cur_b, int* __restrict__ row_b) {
  __shared__ int sdata[1024];
  int tid = threadIdx.x;
  for (int which = 0; which < 2; ++which) {
    int* cnt = which ? cur_b : cur_f;
    int* row = which ? row_b : row_f;
    int base = tid * 13;
    int vals[13];
    int tot = 0;
    for (int k = 0; k < 13; ++k) {
      int idx = base + k;
      int v = (idx < BN) ? cnt[idx] : 0;
      vals[k] = v; tot += v;
    }
    sdata[tid] = tot;
    __syncthreads();
    for (int off = 1; off < 1024; off <<= 1) {
      int add = (tid >= off) ? sdata[tid - off] : 0;
      __syncthreads();
      sdata[tid] += add;
      __syncthreads();
    }
    int running = sdata[tid] - tot;  // exclusive
    for (int k = 0; k < 13; ++k) {
      int idx = base + k;
      if (idx < BN) { row[idx] = running; cnt[idx] = running; running += vals[k]; }
    }
    if (tid == 1023) row[BN] = sdata[1023];
    __syncthreads();
  }
}

__global__ void k_fill(const int* __restrict__ src, const int* __restrict__ dst,
                       const float* __restrict__ w,
                       int* __restrict__ cur_f, int2* __restrict__ ce_f,
                       int* __restrict__ cur_b, int2* __restrict__ ce_b) {
  int e = blockIdx.x * 256 + threadIdx.x;
  if (e < NE) {
    int s = src[e], t = dst[e];
    int wb = __float_as_int(w[e]);
    int p = atomicAdd(&cur_f[t], 1); ce_f[p] = make_int2(s, wb);
    int q = atomicAdd(&cur_b[s], 1); ce_b[q] = make_int2(t, wb);
  }
}

// ---------------- init linear ----------------
__global__ void k_init(const float* __restrict__ x, const float* __restrict__ iw,
                       const float* __restrict__ ib, float* __restrict__ h) {
  int idx = blockIdx.x * 256 + threadIdx.x;
  if (idx >= BN * 13 * 32) return;
  int c = idx & 31;
  int r = idx >> 5;          // r = tau*BN + n
  int n = r % BN;
  int tau = r / BN;
  float x0 = x[(n * 13 + tau) * 2 + 0];
  float x1 = x[(n * 13 + tau) * 2 + 1];
  h[idx] = fmaf(x0, iw[c], fmaf(x1, iw[32 + c], ib[c]));
}

// ---------------- weight pre-pack ----------------
__global__ void k_pack(const float* __restrict__ skip_w, const float* __restrict__ skip_b,
                       const float* __restrict__ w0, const float* __restrict__ w1,
                       const float* __restrict__ gcn_w,
                       const float* __restrict__ filt_w, const float* __restrict__ gate_w,
                       unsigned short* __restrict__ SWb, unsigned short* __restrict__ W0T,
                       unsigned short* __restrict__ W1T, float* __restrict__ bsum,
                       unsigned short* __restrict__ Gg16, uint2* __restrict__ WQ2) {
  int id = blockIdx.x * 256 + threadIdx.x;
  if (id < 65536) {          // SWb[j][k=l*32+c] = skip_w[l][j][c]  (bf16, head)
    int j = id >> 8, k = id & 255;
    SWb[id] = to_bf16(skip_w[((k >> 5) * 256 + j) * 32 + (k & 31)]);
  }
  if (id < 131072) {         // W0T[jo][k] = w0[k][jo]  (bf16, head)
    int jo = id >> 8, k = id & 255;
    W0T[id] = to_bf16(w0[k * 512 + jo]);
  }
  if (id < 8192) {           // W1T[n][k] = w1[k][n], n padded to 16  (bf16, head)
    int n = id >> 9, k = id & 511;
    W1T[id] = (n < 12) ? to_bf16(w1[k * 12 + n]) : (unsigned short)0;
  }
  if (id < 256) {
    float s = 0.f;
    for (int l = 0; l < 8; ++l) s += skip_b[l * 256 + id];
    bsum[id] = s;
  }
  if (id < 49152) {          // Gg16[l][co][k=a*32+ci] = gcn_w[l][a][ci][co]  (fp16)
    int l = id / 6144, rem = id % 6144;
    int co = rem / 192, k = rem % 192;
    int a = k >> 5, ci = k & 31;
    Gg16[id] = to_f16(gcn_w[((l * 6 + a) * 32 + ci) * 32 + co]);
  }
  if (id < 7168) {           // WQ2[(l-1)*1024 + ci*32+co] = {h2(f0,g0), h2(f1,g1)} for l=1..7
    int l = id / 1024 + 1, rem = id % 1024;
    int ci = rem >> 5, co = rem & 31;
    const float* fw = filt_w + l * 2048;
    const float* gw = gate_w + l * 2048;
    __half2 a, b;
    a.x = __float2half(fw[(co * 32 + ci) * 2 + 0]); a.y = __float2half(gw[(co * 32 + ci) * 2 + 0]);
    b.x = __float2half(fw[(co * 32 + ci) * 2 + 1]); b.y = __float2half(gw[(co * 32 + ci) * 2 + 1]);
    WQ2[id] = make_uint2(h2u(a), h2u(b));
  }
}

// ---------------- standalone gated TCN (layer 0 only): fp16 t out ----------------
template<int LIN, int D, int TPAD>
__global__ __launch_bounds__(256) void k_tcn(const float* __restrict__ h_in, unsigned short* __restrict__ t_out,
    const float* __restrict__ fw, const float* __restrict__ fb,
    const float* __restrict__ gw, const float* __restrict__ gb) {
  constexpr int LOUT = LIN - D;
  __shared__ __align__(16) float wq[32 * 32 * 4];
  __shared__ float hl[8][LIN * 32];
  int tid = threadIdx.x;
  for (int f = tid; f < 4096; f += 256) {
    int e = f & 3, co = (f >> 2) & 31, ci = f >> 7;
    const float* srcw = (e < 2) ? fw : gw;
    wq[f] = srcw[(co * 32 + ci) * 2 + (e & 1)];
  }
  int n0 = blockIdx.x * 8;
  for (int i = tid; i < 8 * LIN * 32; i += 256) {
    int c = i & 31, r = i >> 5;
    int nl = r / LIN, tau = r % LIN;
    hl[nl][tau * 32 + c] = h_in[(tau * BN + n0 + nl) * 32 + c];
  }
  __syncthreads();
  int nl = tid >> 5, co = tid & 31;
  int n = n0 + nl;
  float accf[LOUT], accg[LOUT];
  float fbv = fb[co], gbv = gb[co];
#pragma unroll
  for (int j = 0; j < LOUT; ++j) { accf[j] = fbv; accg[j] = gbv; }
#pragma unroll
  for (int ci = 0; ci < 32; ++ci) {
    float4 wv = *(const float4*)&wq[(ci * 32 + co) * 4];
    float xr[LIN];
#pragma unroll
    for (int t = 0; t < LIN; ++t) xr[t] = hl[nl][t * 32 + ci];
#pragma unroll
    for (int j = 0; j < LOUT; ++j) {
      accf[j] = fmaf(xr[j], wv.x, accf[j]);
      accf[j] = fmaf(xr[j + D], wv.y, accf[j]);
      accg[j] = fmaf(xr[j], wv.z, accg[j]);
      accg[j] = fmaf(xr[j + D], wv.w, accg[j]);
    }
  }
#pragma unroll
  for (int j = 0; j < TPAD; ++j) {
    unsigned short v = 0;
    if (j < LOUT) v = to_f16(fast_tanh(accf[j < LOUT ? j : 0]) * fast_sig(accg[j < LOUT ? j : 0]));
    t_out[(n * TPAD + j) * 32 + co] = v;
  }
}

// ---------------- gather (fp16 packed math) ----------------
// A: flattened [3 hops][NT][2 half2]
template<int TPAD, int NT>
__device__ __forceinline__ void gather_dir(const unsigned short* __restrict__ t_in,
    int e0, int e1, const int2* __restrict__ ce, int rowoff0, __half2* A) {
  constexpr int EB = 4;
  int e = e0;
  for (; e + EB <= e1; e += EB) {
    int2 c[EB];
    uint2 u[EB][NT];
#pragma unroll
    for (int k = 0; k < EB; ++k) c[k] = ce[e + k];
#pragma unroll
    for (int k = 0; k < EB; ++k) {
      const unsigned short* p = t_in + c[k].x * (TPAD * 32) + rowoff0;
#pragma unroll
      for (int j = 0; j < NT; ++j) u[k][j] = *(const uint2*)(p + j * 32);
    }
#pragma unroll
    for (int k = 0; k < EB; ++k) {
      float w1 = __int_as_float(c[k].y), w2 = w1 * w1, w3 = w2 * w1;
      __half2 wh0 = __float2half2_rn(w1), wh1 = __float2half2_rn(w2), wh2 = __float2half2_rn(w3);
#pragma unroll
      for (int j = 0; j < NT; ++j) {
        __half2 v0 = u2h(u[k][j].x), v1 = u2h(u[k][j].y);
        A[(0 * NT + j) * 2 + 0] = __hfma2(wh0, v0, A[(0 * NT + j) * 2 + 0]);
        A[(0 * NT + j) * 2 + 1] = __hfma2(wh0, v1, A[(0 * NT + j) * 2 + 1]);
        A[(1 * NT + j) * 2 + 0] = __hfma2(wh1, v0, A[(1 * NT + j) * 2 + 0]);
        A[(1 * NT + j) * 2 + 1] = __hfma2(wh1, v1, A[(1 * NT + j) * 2 + 1]);
        A[(2 * NT + j) * 2 + 0] = __hfma2(wh2, v0, A[(2 * NT + j) * 2 + 0]);
        A[(2 * NT + j) * 2 + 1] = __hfma2(wh2, v1, A[(2 * NT + j) * 2 + 1]);
      }
    }
  }
  for (; e < e1; ++e) {
    int2 c = ce[e];
    float w1 = __int_as_float(c.y), w2 = w1 * w1, w3 = w2 * w1;
    __half2 wh0 = __float2half2_rn(w1), wh1 = __float2half2_rn(w2), wh2 = __float2half2_rn(w3);
    const unsigned short* p = t_in + c.x * (TPAD * 32) + rowoff0;
#pragma unroll
    for (int j = 0; j < NT; ++j) {
      uint2 u = *(const uint2*)(p + j * 32);
      __half2 v0 = u2h(u.x), v1 = u2h(u.y);
      A[(0 * NT + j) * 2 + 0] = __hfma2(wh0, v0, A[(0 * NT + j) * 2 + 0]);
      A[(0 * NT + j) * 2 + 1] = __hfma2(wh0, v1, A[(0 * NT + j) * 2 + 1]);
      A[(1 * NT + j) * 2 + 0] = __hfma2(wh1, v0, A[(1 * NT + j) * 2 + 0]);
      A[(1 * NT + j) * 2 + 1] = __hfma2(wh1, v1, A[(1 * NT + j) * 2 + 1]);
      A[(2 * NT + j) * 2 + 0] = __hfma2(wh2, v0, A[(2 * NT + j) * 2 + 0]);
      A[(2 * NT + j) * 2 + 1] = __hfma2(wh2, v1, A[(2 * NT + j) * 2 + 1]);
    }
  }
}

// ---------------- fused layer: diffusion agg (MFMA f16) + residual + next-layer TCN ----------------
template<int LOUT, int D, int TPAD, int D2, int TPAD2, bool LAST>
__global__ __launch_bounds__(128, 2) void k_fused(
    const unsigned short* __restrict__ t_in,
    const float* __restrict__ h_in, float* __restrict__ h_out,
    float* __restrict__ lastcol, unsigned short* __restrict__ t_next,
    const int* __restrict__ row_f, const int2* __restrict__ ce_f,
    const int* __restrict__ row_b, const int2* __restrict__ ce_b,
    const unsigned short* __restrict__ Wg,    // [32][192] fp16 B^T
    const float* __restrict__ bias,
    const uint2* __restrict__ WQn,            // [1024] next-layer conv weights (half2 pairs)
    const float* __restrict__ fbn, const float* __restrict__ gbn) {
  constexpr int NT = TPAD / 4;
  constexpr int LIN2 = LOUT;
  constexpr int LOUT2 = LAST ? 1 : (LOUT - D2);
  __shared__ __align__(16) unsigned short Zl[4 * TPAD * ZSTRIDE];
  __shared__ __align__(16) uint2 wq2s[1024];
  __shared__ float hbuf[4 * LIN2 * 33];
  int tid = threadIdx.x;
  if (!LAST) {
    for (int i = tid; i < 1024; i += 128) wq2s[i] = WQn[i];
  }
  int nl = tid >> 5, lane32 = tid & 31;
  int tl = lane32 >> 3;
  int c4 = (lane32 & 7) << 2;
  int n0 = blockIdx.x * 4;
  int n = n0 + nl;
  int rowoff0 = (tl * NT) * 32 + c4;
  int ef0 = row_f[n], ef1 = row_f[n + 1];
  int eb0 = row_b[n], eb1 = row_b[n + 1];
  __half2 acc[6 * NT * 2];
  __half2 zero = __float2half2_rn(0.f);
#pragma unroll
  for (int i = 0; i < 6 * NT * 2; ++i) acc[i] = zero;
  gather_dir<TPAD, NT>(t_in, ef0, ef1, ce_f, rowoff0, acc);
  gather_dir<TPAD, NT>(t_in, eb0, eb1, ce_b, rowoff0, acc + 3 * NT * 2);
  // z -> LDS fp16 A-tile: row m = nl*TPAD + tl*NT + j, k = a*32 + c4
#pragma unroll
  for (int j = 0; j < NT; ++j) {
    int m = nl * TPAD + tl * NT + j;
#pragma unroll
    for (int a = 0; a < 6; ++a) {
      uint2 v = make_uint2(h2u(acc[(a * NT + j) * 2 + 0]), h2u(acc[(a * NT + j) * 2 + 1]));
      *(uint2*)(&Zl[m * ZSTRIDE + a * 32 + c4]) = v;
    }
  }
  __syncthreads();
  // MFMA: D[4*TPAD rows][32 co] = Z[4*TPAD][192] @ Wg[192][32]; 2 waves, TPAD/2 units
  int wave = tid >> 6, lane = tid & 63;
  int m16 = lane & 15, q = lane >> 4;
#pragma unroll
  for (int i = 0; i < NT; ++i) {
    int u = wave * NT + i;
    int mt = u >> 1, nt = u & 1;
    f32x4 dacc = (f32x4){0.f, 0.f, 0.f, 0.f};
#pragma unroll
    for (int ks = 0; ks < 6; ++ks) {
      f16x8 av = *(const f16x8*)(&Zl[(mt * 16 + m16) * ZSTRIDE + ks * 32 + q * 8]);
      f16x8 bv = *(const f16x8*)((const _Float16*)Wg + (nt * 16 + m16) * 192 + ks * 32 + q * 8);
      dacc = mfma16h(av, bv, dacc);
    }
    int co = nt * 16 + m16;
    float bco = bias[co];
#pragma unroll
    for (int r = 0; r < 4; ++r) {
      int mm = mt * 16 + q * 4 + r;           // C/D: col=lane&15, row=q*4+r
      int node = n0 + mm / TPAD;
      int tau = mm % TPAD;
      if (tau < LOUT) {
        float rres = h_in[((tau + D) * BN + node) * 32 + co];
        float o = dacc[r] + bco + rres;
        h_out[(tau * BN + node) * 32 + co] = o;
        hbuf[(mm / TPAD) * (LIN2 * 33) + tau * 33 + co] = o;
        if (tau == LOUT - 1) lastcol[node * 32 + co] = o;
      }
    }
  }
  if (!LAST) {
    __syncthreads();
    // next-layer TCN: thread (nl, co); conv over hbuf rows
    int co = lane32;
    float accf[LOUT2], accg[LOUT2];
    float fbv = fbn[co], gbv = gbn[co];
#pragma unroll
    for (int j = 0; j < LOUT2; ++j) { accf[j] = fbv; accg[j] = gbv; }
    const float* hb = &hbuf[nl * (LIN2 * 33)];
#pragma unroll
    for (int ci = 0; ci < 32; ++ci) {
      uint2 wp = wq2s[ci * 32 + co];
      __half2 wa = u2h(wp.x), wb = u2h(wp.y);
      float wf0 = __low2float(wa), wg0 = __high2float(wa);
      float wf1 = __low2float(wb), wg1 = __high2float(wb);
      float xr[LIN2];
#pragma unroll
      for (int t = 0; t < LIN2; ++t) xr[t] = hb[t * 33 + ci];
#pragma unroll
      for (int j = 0; j < LOUT2; ++j) {
        accf[j] = fmaf(xr[j], wf0, accf[j]);
        accf[j] = fmaf(xr[j + D2], wf1, accf[j]);
        accg[j] = fmaf(xr[j], wg0, accg[j]);
        accg[j] = fmaf(xr[j + D2], wg1, accg[j]);
      }
    }
#pragma unroll
    for (int j = 0; j < TPAD2; ++j) {
      unsigned short v = 0;
      if (j < LOUT2) v = to_f16(fast_tanh(accf[j < LOUT2 ? j : 0]) * fast_sig(accg[j < LOUT2 ? j : 0]));
      t_next[(n * TPAD2 + j) * 32 + co] = v;
    }
  }
}

// ------------- fused MFMA head (bf16, unchanged) -------------
__device__ __forceinline__ bf16x8 ldsA(const unsigned short* buf, int stride, int row, int ks, int q) {
  int unit = ks * 4 + q;
  int addr = row * stride + ((unit ^ (row & 7)) << 3);
  return *(const bf16x8*)(buf + addr);
}

__global__ __launch_bounds__(256) void k_final(const float* __restrict__ lastcol,
    const unsigned short* __restrict__ SWb, const unsigned short* __restrict__ W0T,
    const unsigned short* __restrict__ W1T, const float* __restrict__ bsum,
    const float* __restrict__ b0, const float* __restrict__ b1,
    float* __restrict__ out) {
  __shared__ __align__(16) unsigned short Z[32 * 256];
  __shared__ __align__(16) unsigned short H[32 * 512];
  int tid = threadIdx.x;
  int wave = tid >> 6, lane = tid & 63;
  int m16 = lane & 15, q = lane >> 4;
  int n0 = blockIdx.x * 32;
#pragma unroll
  for (int it = 0; it < 32; ++it) {
    int id = it * 256 + tid;
    int m = id >> 8, k = id & 255;
    float v = lastcol[((k >> 5) * BN + n0 + m) * 32 + (k & 31)];
    Z[m * 256 + (((k >> 3) ^ (m & 7)) << 3) + (k & 7)] = to_bf16(v);
  }
  __syncthreads();
  f32x4 acc1[2][4];
#pragma unroll
  for (int mt = 0; mt < 2; ++mt)
#pragma unroll
    for (int i = 0; i < 4; ++i) acc1[mt][i] = (f32x4){0.f, 0.f, 0.f, 0.f};
#pragma unroll
  for (int ks = 0; ks < 8; ++ks) {
    bf16x8 a0 = ldsA(Z, 256, m16, ks, q);
    bf16x8 a1 = ldsA(Z, 256, 16 + m16, ks, q);
#pragma unroll
    for (int i = 0; i < 4; ++i) {
      int j = (wave * 4 + i) * 16 + m16;
      bf16x8 b = *(const bf16x8*)(SWb + j * 256 + ks * 32 + q * 8);
      acc1[0][i] = mfma16b(a0, b, acc1[0][i]);
      acc1[1][i] = mfma16b(a1, b, acc1[1][i]);
    }
  }
  __syncthreads();
#pragma unroll
  for (int i = 0; i < 4; ++i) {
    int j = (wave * 4 + i) * 16 + m16;
    float bs = bsum[j];
#pragma unroll
    for (int mt = 0; mt < 2; ++mt)
#pragma unroll
      for (int r = 0; r < 4; ++r) {
        int row = mt * 16 + q * 4 + r;
        float v = fmaxf(acc1[mt][i][r] + bs, 0.f);
        Z[row * 256 + (((j >> 3) ^ (row & 7)) << 3) + (j & 7)] = to_bf16(v);
      }
  }
  __syncthreads();
  f32x4 acc2[2][8];
#pragma unroll
  for (int mt = 0; mt < 2; ++mt)
#pragma unroll
    for (int i = 0; i < 8; ++i) acc2[mt][i] = (f32x4){0.f, 0.f, 0.f, 0.f};
#pragma unroll
  for (int ks = 0; ks < 8; ++ks) {
    bf16x8 a0 = ldsA(Z, 256, m16, ks, q);
    bf16x8 a1 = ldsA(Z, 256, 16 + m16, ks, q);
#pragma unroll
    for (int i = 0; i < 8; ++i) {
      int jo = (wave * 8 + i) * 16 + m16;
      bf16x8 b = *(const bf16x8*)(W0T + jo * 256 + ks * 32 + q * 8);
      acc2[0][i] = mfma16b(a0, b, acc2[0][i]);
      acc2[1][i] = mfma16b(a1, b, acc2[1][i]);
    }
  }
#pragma unroll
  for (int i = 0; i < 8; ++i) {
    int jo = (wave * 8 + i) * 16 + m16;
    float b0v = b0[jo];
#pragma unroll
    for (int mt = 0; mt < 2; ++mt)
#pragma unroll
      for (int r = 0; r < 4; ++r) {
        int row = mt * 16 + q * 4 + r;
        float v = fmaxf(acc2[mt][i][r] + b0v, 0.f);
        H[row * 512 + (((jo >> 3) ^ (row & 7)) << 3) + (jo & 7)] = to_bf16(v);
      }
  }
  __syncthreads();
  if (wave < 2) {
    f32x4 acc3 = (f32x4){0.f, 0.f, 0.f, 0.f};
#pragma unroll
    for (int ks = 0; ks < 16; ++ks) {
      bf16x8 a = ldsA(H, 512, wave * 16 + m16, ks, q);
      bf16x8 b = *(const bf16x8*)(W1T + m16 * 512 + ks * 32 + q * 8);
      acc3 = mfma16b(a, b, acc3);
    }
    if (m16 < 12) {
      float bv = b1[m16];
#pragma unroll
      for (int r = 0; r < 4; ++r)
        out[(n0 + wave * 16 + q * 4 + r) * 12 + m16] = acc3[r] + bv;
    }
  }
}

extern "C" void kernel_launch(void* const* d_in, const int* in_sizes, int n_in,
                              void* d_out, int out_size, void* d_ws, size_t ws_size,
                              hipStream_t stream) {
  const float* x      = (const float*)d_in[0];
  const int*   esrc   = (const int*)d_in[1];
  const int*   edst   = (const int*)d_in[2];
  const float* ew     = (const float*)d_in[3];
  const float* init_w = (const float*)d_in[4];
  const float* init_b = (const float*)d_in[5];
  const float* filt_w = (const float*)d_in[6];
  const float* filt_b = (const float*)d_in[7];
  const float* gate_w = (const float*)d_in[8];
  const float* gate_b = (const float*)d_in[9];
  const float* gcn_w  = (const float*)d_in[10];
  const float* gcn_b  = (const float*)d_in[11];
  const float* skip_w = (const float*)d_in[12];
  const float* skip_b = (const float*)d_in[13];
  const float* w0     = (const float*)d_in[14];
  const float* b0     = (const float*)d_in[15];
  const float* w1     = (const float*)d_in[16];
  const float* b1     = (const float*)d_in[17];
  float* out = (float*)d_out;

  float* base = (float*)d_ws;
  float* hA      = base;                        // 13*BN*32 f32
  float* hB      = hA + 13 * BN * 32;           // 13*BN*32 f32
  unsigned short* tA = (unsigned short*)(hB + 13 * BN * 32);  // 12*BN*32 halves
  unsigned short* tB = tA + 12 * BN * 32;                     // 12*BN*32 halves
  float* lastcol = (float*)(tB + 12 * BN * 32); // 8*BN*32 f32
  int* row_f = (int*)(lastcol + 8 * BN * 32);   // BN+2
  int* row_b = row_f + (BN + 2);                // BN+2
  int* cur_f = row_b + (BN + 2);                // BN
  int* cur_b = cur_f + BN;                      // BN
  int2* ce_f = (int2*)(cur_b + BN);             // NE int2
  int2* ce_b = ce_f + NE;                       // NE int2
  unsigned short* SWb  = (unsigned short*)(ce_b + NE);  // 65536 halves
  unsigned short* W0T  = SWb + 65536;                   // 131072 halves
  unsigned short* W1T  = W0T + 131072;                  // 8192 halves
  unsigned short* Gg16 = W1T + 8192;                    // 49152 halves
  uint2* WQ2   = (uint2*)(Gg16 + 49152);                // 7168 uint2
  float* bsumv = (float*)(WQ2 + 7168);                  // 256 f32

  hipMemsetAsync(cur_f, 0, 2 * BN * sizeof(int), stream);
  const int egrid = (NE + 255) / 256;
  k_count<<<egrid, 256, 0, stream>>>(esrc, edst, cur_f, cur_b);
  k_scan<<<1, 1024, 0, stream>>>(cur_f, row_f, cur_b, row_b);
  k_fill<<<egrid, 256, 0, stream>>>(esrc, edst, ew, cur_f, ce_f, cur_b, ce_b);
  k_init<<<(BN * 13 * 32 + 255) / 256, 256, 0, stream>>>(x, init_w, init_b, hA);
  k_pack<<<512, 256, 0, stream>>>(skip_w, skip_b, w0, w1, gcn_w, filt_w, gate_w,
                                  SWb, W0T, W1T, bsumv, Gg16, WQ2);

  // layer 0 TCN (standalone)
  k_tcn<13, 1, 12><<<BN / 8, 256, 0, stream>>>(hA, tA, filt_w, filt_b, gate_w, gate_b);

  // fused layers: agg(l) + TCN(l+1)
#define FUSED(l, LOUTv, Dv, TPv, D2v, TP2v, LASTv, tin, tout, hin, hout) \
  k_fused<LOUTv, Dv, TPv, D2v, TP2v, LASTv><<<BN / 4, 128, 0, stream>>>( \
      tin, hin, hout, lastcol + l * BN * 32, tout, row_f, ce_f, row_b, ce_b, \
      Gg16 + l * 6144, gcn_b + l * 32, WQ2 + l * 1024, filt_b + (l + 1) * 32, gate_b + (l + 1) * 32);

  FUSED(0, 12, 1, 12, 2, 12, false, tA, tB, hA, hB)
  FUSED(1, 10, 2, 12, 1, 12, false, tB, tA, hB, hA)
  FUSED(2,  9, 1, 12, 2,  8, false, tA, tB, hA, hB)
  FUSED(3,  7, 2,  8, 1,  8, false, tB, tA, hB, hA)
  FUSED(4,  6, 1,  8, 2,  4, false, tA, tB, hA, hB)
  FUSED(5,  4, 2,  4, 1,  4, false, tB, tA, hB, hA)
  FUSED(6,  3, 1,  4, 2,  4, false, tA, tB, hA, hB)
#undef FUSED
  // last layer: agg only (WQ index clamped to valid memory; TCN skipped at compile time)
  k_fused<1, 2, 4, 2, 4, true><<<BN / 4, 128, 0, stream>>>(
      tB, hB, hA, lastcol + 7 * BN * 32, tA, row_f, ce_f, row_b, ce_b,
      Gg16 + 7 * 6144, gcn_b + 7 * 32, WQ2, filt_b, gate_b);

  k_final<<<BN / 32, 256, 0, stream>>>(lastcol, SWb, W0T, W1T, bsumv, b0, b1, out);
}

// Round 8
// 654.166 us; speedup vs baseline: 1.1613x; 1.1317x over previous
//
#include <hip/hip_runtime.h>
#include <hip/hip_fp16.h>

#define BN 13248
#define NE 211968
#define ZSTRIDE 200   // halves per Z row (192 + 8 pad)

typedef __attribute__((ext_vector_type(8))) short bf16x8;
typedef __attribute__((ext_vector_type(8))) _Float16 f16x8;
typedef __attribute__((ext_vector_type(4))) float f32x4;

__device__ __forceinline__ f32x4 mfma16b(bf16x8 a, bf16x8 b, f32x4 c) {
  return __builtin_amdgcn_mfma_f32_16x16x32_bf16(a, b, c, 0, 0, 0);
}
__device__ __forceinline__ f32x4 mfma16h(f16x8 a, f16x8 b, f32x4 c) {
  return __builtin_amdgcn_mfma_f32_16x16x32_f16(a, b, c, 0, 0, 0);
}

__device__ __forceinline__ unsigned short to_bf16(float v) {
  unsigned bits = __float_as_uint(v);
  return (unsigned short)((bits + 0x7FFFu + ((bits >> 16) & 1u)) >> 16);
}
__device__ __forceinline__ unsigned short to_f16(float v) {
  union { __half h; unsigned short s; } u; u.h = __float2half(v); return u.s;
}
__device__ __forceinline__ unsigned h2u(__half2 h) {
  union { __half2 h; unsigned u; } v; v.h = h; return v.u;
}
__device__ __forceinline__ __half2 u2h(unsigned u) {
  union { unsigned u; __half2 h; } v; v.u = u; return v.h;
}

__device__ __forceinline__ float fast_tanh(float x) {
  float e2 = __expf(2.f * x);
  return 1.f - 2.f / (e2 + 1.f);
}
__device__ __forceinline__ float fast_sig(float x) {
  return 1.f / (1.f + __expf(-x));
}

// ---------------- CSR build ----------------
__global__ void k_count(const int* __restrict__ src, const int* __restrict__ dst,
                        int* __restrict__ cur_f, int* __restrict__ cur_b) {
  int e = blockIdx.x * 256 + threadIdx.x;
  if (e < NE) {
    atomicAdd(&cur_f[dst[e]], 1);
    atomicAdd(&cur_b[src[e]], 1);
  }
}

__global__ void k_scan(int* __restrict__ cur_f, int* __restrict__ row_f,
                       int* __restrict__ cur_b, int* __restrict__ row_b) {
  __shared__ int sdata[1024];
  int tid = threadIdx.x;
  for (int which = 0; which < 2; ++which) {
    int* cnt = which ? cur_b : cur_f;
    int* row = which ? row_b : row_f;
    int base = tid * 13;
    int vals[13];
    int tot = 0;
    for (int k = 0; k < 13; ++k) {
      int idx = base + k;
      int v = (idx < BN) ? cnt[idx] : 0;
      vals[k] = v; tot += v;
    }
    sdata[tid] = tot;
    __syncthreads();
    for (int off = 1; off < 1024; off <<= 1) {
      int add = (tid >= off) ? sdata[tid - off] : 0;
      __syncthreads();
      sdata[tid] += add;
      __syncthreads();
    }
    int running = sdata[tid] - tot;  // exclusive
    for (int k = 0; k < 13; ++k) {
      int idx = base + k;
      if (idx < BN) { row[idx] = running; cnt[idx] = running; running += vals[k]; }
    }
    if (tid == 1023) row[BN] = sdata[1023];
    __syncthreads();
  }
}

__global__ void k_fill(const int* __restrict__ src, const int* __restrict__ dst,
                       const float* __restrict__ w,
                       int* __restrict__ cur_f, int2* __restrict__ ce_f,
                       int* __restrict__ cur_b, int2* __restrict__ ce_b) {
  int e = blockIdx.x * 256 + threadIdx.x;
  if (e < NE) {
    int s = src[e], t = dst[e];
    int wb = __float_as_int(w[e]);
    int p = atomicAdd(&cur_f[t], 1); ce_f[p] = make_int2(s, wb);
    int q = atomicAdd(&cur_b[s], 1); ce_b[q] = make_int2(t, wb);
  }
}

// ---------------- init linear ----------------
__global__ void k_init(const float* __restrict__ x, const float* __restrict__ iw,
                       const float* __restrict__ ib, float* __restrict__ h) {
  int idx = blockIdx.x * 256 + threadIdx.x;
  if (idx >= BN * 13 * 32) return;
  int c = idx & 31;
  int r = idx >> 5;          // r = tau*BN + n
  int n = r % BN;
  int tau = r / BN;
  float x0 = x[(n * 13 + tau) * 2 + 0];
  float x1 = x[(n * 13 + tau) * 2 + 1];
  h[idx] = fmaf(x0, iw[c], fmaf(x1, iw[32 + c], ib[c]));
}

// ---------------- weight pre-pack ----------------
__global__ void k_pack(const float* __restrict__ skip_w, const float* __restrict__ skip_b,
                       const float* __restrict__ w0, const float* __restrict__ w1,
                       const float* __restrict__ gcn_w,
                       const float* __restrict__ filt_w, const float* __restrict__ gate_w,
                       unsigned short* __restrict__ SWb, unsigned short* __restrict__ W0T,
                       unsigned short* __restrict__ W1T, float* __restrict__ bsum,
                       unsigned short* __restrict__ Gg16, uint2* __restrict__ WQ2) {
  int id = blockIdx.x * 256 + threadIdx.x;
  if (id < 65536) {          // SWb[j][k=l*32+c] = skip_w[l][j][c]  (bf16, head)
    int j = id >> 8, k = id & 255;
    SWb[id] = to_bf16(skip_w[((k >> 5) * 256 + j) * 32 + (k & 31)]);
  }
  if (id < 131072) {         // W0T[jo][k] = w0[k][jo]  (bf16, head)
    int jo = id >> 8, k = id & 255;
    W0T[id] = to_bf16(w0[k * 512 + jo]);
  }
  if (id < 8192) {           // W1T[n][k] = w1[k][n], n padded to 16  (bf16, head)
    int n = id >> 9, k = id & 511;
    W1T[id] = (n < 12) ? to_bf16(w1[k * 12 + n]) : (unsigned short)0;
  }
  if (id < 256) {
    float s = 0.f;
    for (int l = 0; l < 8; ++l) s += skip_b[l * 256 + id];
    bsum[id] = s;
  }
  if (id < 49152) {          // Gg16[l][co][k=a*32+ci] = gcn_w[l][a][ci][co]  (fp16)
    int l = id / 6144, rem = id % 6144;
    int co = rem / 192, k = rem % 192;
    int a = k >> 5, ci = k & 31;
    Gg16[id] = to_f16(gcn_w[((l * 6 + a) * 32 + ci) * 32 + co]);
  }
  if (id < 7168) {           // WQ2[(l-1)*1024 + ci*32+co] = {h2(f0,g0), h2(f1,g1)} for l=1..7
    int l = id / 1024 + 1, rem = id % 1024;
    int ci = rem >> 5, co = rem & 31;
    const float* fw = filt_w + l * 2048;
    const float* gw = gate_w + l * 2048;
    __half2 a, b;
    a.x = __float2half(fw[(co * 32 + ci) * 2 + 0]); a.y = __float2half(gw[(co * 32 + ci) * 2 + 0]);
    b.x = __float2half(fw[(co * 32 + ci) * 2 + 1]); b.y = __float2half(gw[(co * 32 + ci) * 2 + 1]);
    WQ2[id] = make_uint2(h2u(a), h2u(b));
  }
}

// ---------------- standalone gated TCN (layer 0 only): fp16 t out ----------------
template<int LIN, int D, int TPAD>
__global__ __launch_bounds__(256) void k_tcn(const float* __restrict__ h_in, unsigned short* __restrict__ t_out,
    const float* __restrict__ fw, const float* __restrict__ fb,
    const float* __restrict__ gw, const float* __restrict__ gb) {
  constexpr int LOUT = LIN - D;
  __shared__ __align__(16) float wq[32 * 32 * 4];
  __shared__ float hl[8][LIN * 32];
  int tid = threadIdx.x;
  for (int f = tid; f < 4096; f += 256) {
    int e = f & 3, co = (f >> 2) & 31, ci = f >> 7;
    const float* srcw = (e < 2) ? fw : gw;
    wq[f] = srcw[(co * 32 + ci) * 2 + (e & 1)];
  }
  int n0 = blockIdx.x * 8;
  for (int i = tid; i < 8 * LIN * 32; i += 256) {
    int c = i & 31, r = i >> 5;
    int nl = r / LIN, tau = r % LIN;
    hl[nl][tau * 32 + c] = h_in[(tau * BN + n0 + nl) * 32 + c];
  }
  __syncthreads();
  int nl = tid >> 5, co = tid & 31;
  int n = n0 + nl;
  float accf[LOUT], accg[LOUT];
  float fbv = fb[co], gbv = gb[co];
#pragma unroll
  for (int j = 0; j < LOUT; ++j) { accf[j] = fbv; accg[j] = gbv; }
#pragma unroll
  for (int ci = 0; ci < 32; ++ci) {
    float4 wv = *(const float4*)&wq[(ci * 32 + co) * 4];
    float xr[LIN];
#pragma unroll
    for (int t = 0; t < LIN; ++t) xr[t] = hl[nl][t * 32 + ci];
#pragma unroll
    for (int j = 0; j < LOUT; ++j) {
      accf[j] = fmaf(xr[j], wv.x, accf[j]);
      accf[j] = fmaf(xr[j + D], wv.y, accf[j]);
      accg[j] = fmaf(xr[j], wv.z, accg[j]);
      accg[j] = fmaf(xr[j + D], wv.w, accg[j]);
    }
  }
#pragma unroll
  for (int j = 0; j < TPAD; ++j) {
    unsigned short v = 0;
    if (j < LOUT) v = to_f16(fast_tanh(accf[j < LOUT ? j : 0]) * fast_sig(accg[j < LOUT ? j : 0]));
    t_out[(n * TPAD + j) * 32 + co] = v;
  }
}

// ---------------- gather (fp16 packed math) ----------------
template<int TPAD, int NT>
__device__ __forceinline__ void gather_dir(const unsigned short* __restrict__ t_in,
    int e0, int e1, const int2* __restrict__ ce, int rowoff0, __half2* A) {
  constexpr int EB = 4;
  int e = e0;
  for (; e + EB <= e1; e += EB) {
    int2 c[EB];
    uint2 u[EB][NT];
#pragma unroll
    for (int k = 0; k < EB; ++k) c[k] = ce[e + k];
#pragma unroll
    for (int k = 0; k < EB; ++k) {
      const unsigned short* p = t_in + c[k].x * (TPAD * 32) + rowoff0;
#pragma unroll
      for (int j = 0; j < NT; ++j) u[k][j] = *(const uint2*)(p + j * 32);
    }
#pragma unroll
    for (int k = 0; k < EB; ++k) {
      float w1 = __int_as_float(c[k].y), w2 = w1 * w1, w3 = w2 * w1;
      __half2 wh0 = __float2half2_rn(w1), wh1 = __float2half2_rn(w2), wh2 = __float2half2_rn(w3);
#pragma unroll
      for (int j = 0; j < NT; ++j) {
        __half2 v0 = u2h(u[k][j].x), v1 = u2h(u[k][j].y);
        A[(0 * NT + j) * 2 + 0] = __hfma2(wh0, v0, A[(0 * NT + j) * 2 + 0]);
        A[(0 * NT + j) * 2 + 1] = __hfma2(wh0, v1, A[(0 * NT + j) * 2 + 1]);
        A[(1 * NT + j) * 2 + 0] = __hfma2(wh1, v0, A[(1 * NT + j) * 2 + 0]);
        A[(1 * NT + j) * 2 + 1] = __hfma2(wh1, v1, A[(1 * NT + j) * 2 + 1]);
        A[(2 * NT + j) * 2 + 0] = __hfma2(wh2, v0, A[(2 * NT + j) * 2 + 0]);
        A[(2 * NT + j) * 2 + 1] = __hfma2(wh2, v1, A[(2 * NT + j) * 2 + 1]);
      }
    }
  }
  for (; e < e1; ++e) {
    int2 c = ce[e];
    float w1 = __int_as_float(c.y), w2 = w1 * w1, w3 = w2 * w1;
    __half2 wh0 = __float2half2_rn(w1), wh1 = __float2half2_rn(w2), wh2 = __float2half2_rn(w3);
    const unsigned short* p = t_in + c.x * (TPAD * 32) + rowoff0;
#pragma unroll
    for (int j = 0; j < NT; ++j) {
      uint2 u = *(const uint2*)(p + j * 32);
      __half2 v0 = u2h(u.x), v1 = u2h(u.y);
      A[(0 * NT + j) * 2 + 0] = __hfma2(wh0, v0, A[(0 * NT + j) * 2 + 0]);
      A[(0 * NT + j) * 2 + 1] = __hfma2(wh0, v1, A[(0 * NT + j) * 2 + 1]);
      A[(1 * NT + j) * 2 + 0] = __hfma2(wh1, v0, A[(1 * NT + j) * 2 + 0]);
      A[(1 * NT + j) * 2 + 1] = __hfma2(wh1, v1, A[(1 * NT + j) * 2 + 1]);
      A[(2 * NT + j) * 2 + 0] = __hfma2(wh2, v0, A[(2 * NT + j) * 2 + 0]);
      A[(2 * NT + j) * 2 + 1] = __hfma2(wh2, v1, A[(2 * NT + j) * 2 + 1]);
    }
  }
}

// ---------------- fused layer: agg (MFMA f16) + residual + next-layer TCN ----------------
// LDS union: phase 1 uses Zl (4*TPAD*ZSTRIDE halves); after MFMA reads complete,
// the same space holds wq2s (8 KB) + hbuf. dacc lives in registers across the barrier.
template<int LOUT, int D, int TPAD, int D2, int TPAD2, bool LAST>
__global__ __launch_bounds__(128, 4) void k_fused(
    const unsigned short* __restrict__ t_in,
    const float* __restrict__ h_in, float* __restrict__ h_out,
    float* __restrict__ lastcol, unsigned short* __restrict__ t_next,
    const int* __restrict__ row_f, const int2* __restrict__ ce_f,
    const int* __restrict__ row_b, const int2* __restrict__ ce_b,
    const unsigned short* __restrict__ Wg,    // [32][192] fp16 B^T
    const float* __restrict__ bias,
    const uint2* __restrict__ WQn,            // [1024] next-layer conv weights (half2 pairs)
    const float* __restrict__ fbn, const float* __restrict__ gbn) {
  constexpr int NT = TPAD / 4;
  constexpr int LIN2 = LOUT;
  constexpr int LOUT2 = LAST ? 1 : (LOUT - D2);
  constexpr int ZBYTES = 4 * TPAD * ZSTRIDE * 2;
  constexpr int PBYTES = LAST ? 0 : (8192 + 4 * LIN2 * 33 * 4);
  constexpr int SBYTES = (ZBYTES > PBYTES) ? ZBYTES : PBYTES;
  __shared__ __align__(16) char smem[SBYTES];
  unsigned short* Zl = (unsigned short*)smem;
  uint2* wq2s = (uint2*)smem;
  float* hbuf = (float*)(smem + 8192);
  int tid = threadIdx.x;
  int nl = tid >> 5, lane32 = tid & 31;
  int tl = lane32 >> 3;
  int c4 = (lane32 & 7) << 2;
  int n0 = blockIdx.x * 4;
  int n = n0 + nl;
  int rowoff0 = (tl * NT) * 32 + c4;
  int ef0 = row_f[n], ef1 = row_f[n + 1];
  int eb0 = row_b[n], eb1 = row_b[n + 1];
  __half2 acc[6 * NT * 2];
  __half2 zero = __float2half2_rn(0.f);
#pragma unroll
  for (int i = 0; i < 6 * NT * 2; ++i) acc[i] = zero;
  gather_dir<TPAD, NT>(t_in, ef0, ef1, ce_f, rowoff0, acc);
  gather_dir<TPAD, NT>(t_in, eb0, eb1, ce_b, rowoff0, acc + 3 * NT * 2);
#pragma unroll
  for (int j = 0; j < NT; ++j) {
    int m = nl * TPAD + tl * NT + j;
#pragma unroll
    for (int a = 0; a < 6; ++a) {
      uint2 v = make_uint2(h2u(acc[(a * NT + j) * 2 + 0]), h2u(acc[(a * NT + j) * 2 + 1]));
      *(uint2*)(&Zl[m * ZSTRIDE + a * 32 + c4]) = v;
    }
  }
  __syncthreads();
  // MFMA: all NT units into registers (Zl stays readable until next barrier)
  int wave = tid >> 6, lane = tid & 63;
  int m16 = lane & 15, q = lane >> 4;
  f32x4 dacc[NT];
#pragma unroll
  for (int i = 0; i < NT; ++i) {
    int u = wave * NT + i;
    int mt = u >> 1, nt = u & 1;
    dacc[i] = (f32x4){0.f, 0.f, 0.f, 0.f};
#pragma unroll
    for (int ks = 0; ks < 6; ++ks) {
      f16x8 av = *(const f16x8*)(&Zl[(mt * 16 + m16) * ZSTRIDE + ks * 32 + q * 8]);
      f16x8 bv = *(const f16x8*)((const _Float16*)Wg + (nt * 16 + m16) * 192 + ks * 32 + q * 8);
      dacc[i] = mfma16h(av, bv, dacc[i]);
    }
  }
  __syncthreads();   // Zl dead; smem becomes wq2s + hbuf
  if (!LAST) {
    for (int i = tid; i < 1024; i += 128) wq2s[i] = WQn[i];
  }
#pragma unroll
  for (int i = 0; i < NT; ++i) {
    int u = wave * NT + i;
    int mt = u >> 1, nt = u & 1;
    int co = nt * 16 + m16;
    float bco = bias[co];
#pragma unroll
    for (int r = 0; r < 4; ++r) {
      int mm = mt * 16 + q * 4 + r;           // C/D: col=lane&15, row=q*4+r
      int node = n0 + mm / TPAD;
      int tau = mm % TPAD;
      if (tau < LOUT) {
        float rres = h_in[((tau + D) * BN + node) * 32 + co];
        float o = dacc[i][r] + bco + rres;
        h_out[(tau * BN + node) * 32 + co] = o;
        if (!LAST) hbuf[(mm / TPAD) * (LIN2 * 33) + tau * 33 + co] = o;
        if (tau == LOUT - 1) lastcol[node * 32 + co] = o;
      }
    }
  }
  if (!LAST) {
    __syncthreads();
    int co = lane32;
    float accf[LOUT2], accg[LOUT2];
    float fbv = fbn[co], gbv = gbn[co];
#pragma unroll
    for (int j = 0; j < LOUT2; ++j) { accf[j] = fbv; accg[j] = gbv; }
    const float* hb = &hbuf[nl * (LIN2 * 33)];
#pragma unroll
    for (int ci = 0; ci < 32; ++ci) {
      uint2 wp = wq2s[ci * 32 + co];
      __half2 wa = u2h(wp.x), wb = u2h(wp.y);
      float wf0 = __low2float(wa), wg0 = __high2float(wa);
      float wf1 = __low2float(wb), wg1 = __high2float(wb);
      float xr[LIN2];
#pragma unroll
      for (int t = 0; t < LIN2; ++t) xr[t] = hb[t * 33 + ci];
#pragma unroll
      for (int j = 0; j < LOUT2; ++j) {
        accf[j] = fmaf(xr[j], wf0, accf[j]);
        accf[j] = fmaf(xr[j + D2], wf1, accf[j]);
        accg[j] = fmaf(xr[j], wg0, accg[j]);
        accg[j] = fmaf(xr[j + D2], wg1, accg[j]);
      }
    }
#pragma unroll
    for (int j = 0; j < TPAD2; ++j) {
      unsigned short v = 0;
      if (j < LOUT2) v = to_f16(fast_tanh(accf[j < LOUT2 ? j : 0]) * fast_sig(accg[j < LOUT2 ? j : 0]));
      t_next[(n * TPAD2 + j) * 32 + co] = v;
    }
  }
}

// ------------- fused MFMA head (bf16) -------------
__device__ __forceinline__ bf16x8 ldsA(const unsigned short* buf, int stride, int row, int ks, int q) {
  int unit = ks * 4 + q;
  int addr = row * stride + ((unit ^ (row & 7)) << 3);
  return *(const bf16x8*)(buf + addr);
}

__global__ __launch_bounds__(256) void k_final(const float* __restrict__ lastcol,
    const unsigned short* __restrict__ SWb, const unsigned short* __restrict__ W0T,
    const unsigned short* __restrict__ W1T, const float* __restrict__ bsum,
    const float* __restrict__ b0, const float* __restrict__ b1,
    float* __restrict__ out) {
  __shared__ __align__(16) unsigned short Z[32 * 256];
  __shared__ __align__(16) unsigned short H[32 * 512];
  int tid = threadIdx.x;
  int wave = tid >> 6, lane = tid & 63;
  int m16 = lane & 15, q = lane >> 4;
  int n0 = blockIdx.x * 32;
#pragma unroll
  for (int it = 0; it < 32; ++it) {
    int id = it * 256 + tid;
    int m = id >> 8, k = id & 255;
    float v = lastcol[((k >> 5) * BN + n0 + m) * 32 + (k & 31)];
    Z[m * 256 + (((k >> 3) ^ (m & 7)) << 3) + (k & 7)] = to_bf16(v);
  }
  __syncthreads();
  f32x4 acc1[2][4];
#pragma unroll
  for (int mt = 0; mt < 2; ++mt)
#pragma unroll
    for (int i = 0; i < 4; ++i) acc1[mt][i] = (f32x4){0.f, 0.f, 0.f, 0.f};
#pragma unroll
  for (int ks = 0; ks < 8; ++ks) {
    bf16x8 a0 = ldsA(Z, 256, m16, ks, q);
    bf16x8 a1 = ldsA(Z, 256, 16 + m16, ks, q);
#pragma unroll
    for (int i = 0; i < 4; ++i) {
      int j = (wave * 4 + i) * 16 + m16;
      bf16x8 b = *(const bf16x8*)(SWb + j * 256 + ks * 32 + q * 8);
      acc1[0][i] = mfma16b(a0, b, acc1[0][i]);
      acc1[1][i] = mfma16b(a1, b, acc1[1][i]);
    }
  }
  __syncthreads();
#pragma unroll
  for (int i = 0; i < 4; ++i) {
    int j = (wave * 4 + i) * 16 + m16;
    float bs = bsum[j];
#pragma unroll
    for (int mt = 0; mt < 2; ++mt)
#pragma unroll
      for (int r = 0; r < 4; ++r) {
        int row = mt * 16 + q * 4 + r;
        float v = fmaxf(acc1[mt][i][r] + bs, 0.f);
        Z[row * 256 + (((j >> 3) ^ (row & 7)) << 3) + (j & 7)] = to_bf16(v);
      }
  }
  __syncthreads();
  f32x4 acc2[2][8];
#pragma unroll
  for (int mt = 0; mt < 2; ++mt)
#pragma unroll
    for (int i = 0; i < 8; ++i) acc2[mt][i] = (f32x4){0.f, 0.f, 0.f, 0.f};
#pragma unroll
  for (int ks = 0; ks < 8; ++ks) {
    bf16x8 a0 = ldsA(Z, 256, m16, ks, q);
    bf16x8 a1 = ldsA(Z, 256, 16 + m16, ks, q);
#pragma unroll
    for (int i = 0; i < 8; ++i) {
      int jo = (wave * 8 + i) * 16 + m16;
      bf16x8 b = *(const bf16x8*)(W0T + jo * 256 + ks * 32 + q * 8);
      acc2[0][i] = mfma16b(a0, b, acc2[0][i]);
      acc2[1][i] = mfma16b(a1, b, acc2[1][i]);
    }
  }
#pragma unroll
  for (int i = 0; i < 8; ++i) {
    int jo = (wave * 8 + i) * 16 + m16;
    float b0v = b0[jo];
#pragma unroll
    for (int mt = 0; mt < 2; ++mt)
#pragma unroll
      for (int r = 0; r < 4; ++r) {
        int row = mt * 16 + q * 4 + r;
        float v = fmaxf(acc2[mt][i][r] + b0v, 0.f);
        H[row * 512 + (((jo >> 3) ^ (row & 7)) << 3) + (jo & 7)] = to_bf16(v);
      }
  }
  __syncthreads();
  if (wave < 2) {
    f32x4 acc3 = (f32x4){0.f, 0.f, 0.f, 0.f};
#pragma unroll
    for (int ks = 0; ks < 16; ++ks) {
      bf16x8 a = ldsA(H, 512, wave * 16 + m16, ks, q);
      bf16x8 b = *(const bf16x8*)(W1T + m16 * 512 + ks * 32 + q * 8);
      acc3 = mfma16b(a, b, acc3);
    }
    if (m16 < 12) {
      float bv = b1[m16];
#pragma unroll
      for (int r = 0; r < 4; ++r)
        out[(n0 + wave * 16 + q * 4 + r) * 12 + m16] = acc3[r] + bv;
    }
  }
}

extern "C" void kernel_launch(void* const* d_in, const int* in_sizes, int n_in,
                              void* d_out, int out_size, void* d_ws, size_t ws_size,
                              hipStream_t stream) {
  const float* x      = (const float*)d_in[0];
  const int*   esrc   = (const int*)d_in[1];
  const int*   edst   = (const int*)d_in[2];
  const float* ew     = (const float*)d_in[3];
  const float* init_w = (const float*)d_in[4];
  const float* init_b = (const float*)d_in[5];
  const float* filt_w = (const float*)d_in[6];
  const float* filt_b = (const float*)d_in[7];
  const float* gate_w = (const float*)d_in[8];
  const float* gate_b = (const float*)d_in[9];
  const float* gcn_w  = (const float*)d_in[10];
  const float* gcn_b  = (const float*)d_in[11];
  const float* skip_w = (const float*)d_in[12];
  const float* skip_b = (const float*)d_in[13];
  const float* w0     = (const float*)d_in[14];
  const float* b0     = (const float*)d_in[15];
  const float* w1     = (const float*)d_in[16];
  const float* b1     = (const float*)d_in[17];
  float* out = (float*)d_out;

  float* base = (float*)d_ws;
  float* hA      = base;                        // 13*BN*32 f32
  float* hB      = hA + 13 * BN * 32;           // 13*BN*32 f32
  unsigned short* tA = (unsigned short*)(hB + 13 * BN * 32);  // 12*BN*32 halves
  unsigned short* tB = tA + 12 * BN * 32;                     // 12*BN*32 halves
  float* lastcol = (float*)(tB + 12 * BN * 32); // 8*BN*32 f32
  int* row_f = (int*)(lastcol + 8 * BN * 32);   // BN+2
  int* row_b = row_f + (BN + 2);                // BN+2
  int* cur_f = row_b + (BN + 2);                // BN
  int* cur_b = cur_f + BN;                      // BN
  int2* ce_f = (int2*)(cur_b + BN);             // NE int2
  int2* ce_b = ce_f + NE;                       // NE int2
  unsigned short* SWb  = (unsigned short*)(ce_b + NE);  // 65536 halves
  unsigned short* W0T  = SWb + 65536;                   // 131072 halves
  unsigned short* W1T  = W0T + 131072;                  // 8192 halves
  unsigned short* Gg16 = W1T + 8192;                    // 49152 halves
  uint2* WQ2   = (uint2*)(Gg16 + 49152);                // 7168 uint2
  float* bsumv = (float*)(WQ2 + 7168);                  // 256 f32

  hipMemsetAsync(cur_f, 0, 2 * BN * sizeof(int), stream);
  const int egrid = (NE + 255) / 256;
  k_count<<<egrid, 256, 0, stream>>>(esrc, edst, cur_f, cur_b);
  k_scan<<<1, 1024, 0, stream>>>(cur_f, row_f, cur_b, row_b);
  k_fill<<<egrid, 256, 0, stream>>>(esrc, edst, ew, cur_f, ce_f, cur_b, ce_b);
  k_init<<<(BN * 13 * 32 + 255) / 256, 256, 0, stream>>>(x, init_w, init_b, hA);
  k_pack<<<512, 256, 0, stream>>>(skip_w, skip_b, w0, w1, gcn_w, filt_w, gate_w,
                                  SWb, W0T, W1T, bsumv, Gg16, WQ2);

  // layer 0 TCN (standalone)
  k_tcn<13, 1, 12><<<BN / 8, 256, 0, stream>>>(hA, tA, filt_w, filt_b, gate_w, gate_b);

  // fused layers: agg(l) + TCN(l+1)
#define FUSED(l, LOUTv, Dv, TPv, D2v, TP2v, LASTv, tin, tout, hin, hout) \
  k_fused<LOUTv, Dv, TPv, D2v, TP2v, LASTv><<<BN / 4, 128, 0, stream>>>( \
      tin, hin, hout, lastcol + l * BN * 32, tout, row_f, ce_f, row_b, ce_b, \
      Gg16 + l * 6144, gcn_b + l * 32, WQ2 + l * 1024, filt_b + (l + 1) * 32, gate_b + (l + 1) * 32);

  FUSED(0, 12, 1, 12, 2, 12, false, tA, tB, hA, hB)
  FUSED(1, 10, 2, 12, 1, 12, false, tB, tA, hB, hA)
  FUSED(2,  9, 1, 12, 2,  8, false, tA, tB, hA, hB)
  FUSED(3,  7, 2,  8, 1,  8, false, tB, tA, hB, hA)
  FUSED(4,  6, 1,  8, 2,  4, false, tA, tB, hA, hB)
  FUSED(5,  4, 2,  4, 1,  4, false, tB, tA, hB, hA)
  FUSED(6,  3, 1,  4, 2,  4, false, tA, tB, hA, hB)
#undef FUSED
  // last layer: agg only
  k_fused<1, 2, 4, 2, 4, true><<<BN / 4, 128, 0, stream>>>(
      tB, hB, hA, lastcol + 7 * BN * 32, tA, row_f, ce_f, row_b, ce_b,
      Gg16 + 7 * 6144, gcn_b + 7 * 32, WQ2, filt_b, gate_b);

  k_final<<<BN / 32, 256, 0, stream>>>(lastcol, SWb, W0T, W1T, bsumv, b0, b1, out);
}